// Round 9
// baseline (215.646 us; speedup 1.0000x reference)
//
#include <hip/hip_runtime.h>
#include <math.h>

#define NB 2
#define NI 64
#define NJ 512
#define NDT 512
#define NDM 80
#define NA 128

#define NEG9    (-1000000000.0f)
#define LOGEPS  (-1000.0f)
#define IDENT   (-1.0e30f)
#define LN512   (6.2383246250f)
#define LN2F    (0.69314718056f)
#define INVLN2  (1.44269504089f)
#define LOGEPS2 (-1442.6950409f)   // -1000/ln2

__device__ __forceinline__ float lse2(float a, float b) {
    float m = fmaxf(a, b);
    float d = fabsf(a - b);
    return m + __logf(1.0f + __expf(-d));
}

// ---- (m,s) pair log-sum in LOG2 domain: value = m + log2(s) ---------------
// pcomb: one dependent exp2 (native v_exp_f32) per combine. exp2 args <= 0
// (mm = max); max-achiever contributes s*2^0, so s stays in [0.5, ~1024]
// given the per-iteration renorm (R5/R6 NaN root cause was the missing renorm).
struct Pair { float m, s; };

__device__ __forceinline__ Pair pcomb(Pair a, Pair b) {
    float mm = fmaxf(a.m, b.m);
    float ss = a.s * exp2f(a.m - mm) + b.s * exp2f(b.m - mm);
    return {mm, ss};
}

// DPP-based combines (ctrl/masks HW-verified in R4/R8).
template<int CTRL, int RM>
__device__ __forceinline__ float dpp_lse(float s) {
    int v = __builtin_amdgcn_update_dpp(__float_as_int(IDENT), __float_as_int(s),
                                        CTRL, RM, 0xf, false);
    return lse2(s, __int_as_float(v));
}
template<int CTRL, int RM>
__device__ __forceinline__ Pair dpp_pcomb(Pair x) {
    int bm = __builtin_amdgcn_update_dpp(__float_as_int(IDENT), __float_as_int(x.m),
                                         CTRL, RM, 0xf, false);
    int bs = __builtin_amdgcn_update_dpp(0, __float_as_int(x.s),
                                         CTRL, RM, 0xf, false);
    Pair b{__int_as_float(bm), __int_as_float(bs)};
    return pcomb(x, b);
}

// Inclusive 64-lane scans (canonical gfx9 row_shr + row_bcast sequence).
__device__ __forceinline__ float wave_lse_scan(float x) {
    x = dpp_lse<0x111, 0xf>(x);
    x = dpp_lse<0x112, 0xf>(x);
    x = dpp_lse<0x114, 0xf>(x);
    x = dpp_lse<0x118, 0xf>(x);
    x = dpp_lse<0x142, 0xa>(x);
    x = dpp_lse<0x143, 0xc>(x);
    return x;
}
__device__ __forceinline__ Pair wave_pair_scan(Pair x) {
    x = dpp_pcomb<0x111, 0xf>(x);
    x = dpp_pcomb<0x112, 0xf>(x);
    x = dpp_pcomb<0x114, 0xf>(x);
    x = dpp_pcomb<0x118, 0xf>(x);
    x = dpp_pcomb<0x142, 0xa>(x);
    x = dpp_pcomb<0x143, 0xc>(x);
    return x;
}

__device__ __forceinline__ float bcast63(float x) {
    return __int_as_float(__builtin_amdgcn_readlane(__float_as_int(x), 63));
}
__device__ __forceinline__ Pair shflup1(Pair x) {
    return { __shfl_up(x.m, 1, 64), __shfl_up(x.s, 1, 64) };
}

// Inclusive 8-element Sklansky lse-scan, depth 3 (k_soft).
__device__ __forceinline__ void sklansky8(const float* q, float* ls) {
    ls[0]=q[0]; ls[2]=q[2]; ls[4]=q[4]; ls[6]=q[6];
    ls[1]=lse2(q[0],q[1]); ls[3]=lse2(q[2],q[3]);
    ls[5]=lse2(q[4],q[5]); ls[7]=lse2(q[6],q[7]);
    ls[2]=lse2(ls[1],ls[2]); ls[3]=lse2(ls[1],ls[3]);
    ls[6]=lse2(ls[5],ls[6]); ls[7]=lse2(ls[5],ls[7]);
    ls[4]=lse2(ls[3],ls[4]); ls[5]=lse2(ls[3],ls[5]);
    ls[6]=lse2(ls[3],ls[6]); ls[7]=lse2(ls[3],ls[7]);
}

// ---------------- K1: projections pm (transposed) and pt ----------------
__global__ __launch_bounds__(128) void k_proj(const float* __restrict__ text,
                                              const float* __restrict__ mel,
                                              const float* __restrict__ mel_w,
                                              const float* __restrict__ mel_b,
                                              const float* __restrict__ text_w,
                                              float* __restrict__ pmT,
                                              float* __restrict__ pt) {
    __shared__ float row[NDT];
    int blk = blockIdx.x;
    int tid = threadIdx.x; // 128
    if (blk < NB * NJ) {
        int b = blk >> 9, j = blk & (NJ - 1);
        if (tid < NDM) row[tid] = mel[(b * NJ + j) * NDM + tid];
        __syncthreads();
        float acc = mel_b[tid];
        #pragma unroll 8
        for (int k = 0; k < NDM; ++k) acc = fmaf(row[k], mel_w[tid * NDM + k], acc);
        pmT[(b * NA + tid) * NJ + j] = acc;
    } else {
        int blk2 = blk - NB * NJ;
        int b = blk2 >> 6, i = blk2 & (NI - 1);
        for (int k = tid; k < NDT; k += 128) row[k] = text[(b * NI + i) * NDT + k];
        __syncthreads();
        float acc = 0.0f;
        #pragma unroll 8
        for (int k = 0; k < NDT; ++k) acc = fmaf(row[k], text_w[tid * NDT + k], acc);
        pt[(b * NI + i) * NA + tid] = acc;
    }
}

// ---------------- K2: energy = sigmoid(tanh(pm+pt)·v_w + v_b + 2*noise) ----------------
__global__ __launch_bounds__(512) void k_energy(const float* __restrict__ pmT,
                                                const float* __restrict__ pt,
                                                const float* __restrict__ v_w,
                                                const float* __restrict__ v_b,
                                                const float* __restrict__ noise,
                                                float* __restrict__ energy) {
    int bi = blockIdx.x;     // b*NI + i
    int j = threadIdx.x;     // 512
    int b = bi >> 6;
    __shared__ float pts[NA];
    __shared__ float vws[NA];
    if (j < NA) { pts[j] = pt[bi * NA + j]; vws[j] = v_w[j]; }
    __syncthreads();
    float acc = 0.0f;
    const float* pmb = pmT + b * NA * NJ + j;
    #pragma unroll 4
    for (int a = 0; a < NA; ++a) {
        float x = pmb[a * NJ] + pts[a];
        float t = __expf(2.0f * x);
        float th = 1.0f - 2.0f / (t + 1.0f);
        acc = fmaf(th, vws[a], acc);
    }
    float x = acc + v_b[0] + 2.0f * noise[bi * NJ + j];
    energy[bi * NJ + j] = 1.0f / (1.0f + __expf(-x));
}

// ---------------- K3: suffix-lse T and denom per (b,i) row (R4-verified) ----------------
__global__ __launch_bounds__(64) void k_suffix(const float* __restrict__ energy,
                                               float* __restrict__ T,
                                               float* __restrict__ denom) {
    int bi = blockIdx.x;
    int lane = threadIdx.x; // 64
    const float4* er = (const float4*)(energy + bi * NJ);
    float4 v0 = er[lane * 2], v1 = er[lane * 2 + 1];
    float q[8] = {v0.x, v0.y, v0.z, v0.w, v1.x, v1.y, v1.z, v1.w};
    float ss[8];
    ss[7] = q[7];
    #pragma unroll
    for (int t = 6; t >= 0; --t) ss[t] = lse2(q[t], ss[t + 1]);
    float tot = ss[0];
    #pragma unroll
    for (int off = 1; off < 64; off <<= 1) {
        float o = __shfl_down(tot, off, 64);
        if (lane + off < 64) tot = lse2(tot, o);
    }
    float offS = __shfl_down(tot, 1, 64);
    if (lane == 63) offS = IDENT;
    float Tl[8];
    #pragma unroll
    for (int t = 0; t < 8; ++t) Tl[t] = lse2(ss[t], offS);
    float4* Tr = (float4*)(T + bi * NJ);
    Tr[lane * 2]     = make_float4(Tl[0], Tl[1], Tl[2], Tl[3]);
    Tr[lane * 2 + 1] = make_float4(Tl[4], Tl[5], Tl[6], Tl[7]);
    // denom[k] = T[k+1]; denom[511] = -1000 + ln(512)
    float nextT0 = __shfl_down(Tl[0], 1, 64);
    float dn[8];
    #pragma unroll
    for (int t = 0; t < 7; ++t) dn[t] = Tl[t + 1];
    dn[7] = (lane == 63) ? (LOGEPS + LN512) : nextT0;
    float4* dr = (float4*)(denom + bi * NJ);
    dr[lane * 2]     = make_float4(dn[0], dn[1], dn[2], dn[3]);
    dr[lane * 2 + 1] = make_float4(dn[4], dn[5], dn[6], dn[7]);
}

// ---------------- K4: sequential forward scan; 8 waves per batch ----------------
// One element per thread (512 threads = NJ). Per iteration: wave-level DPP
// pair scan -> LDS wave totals -> barrier -> 8-total tree (exclusive offset
// per wave, uniform switch) -> Pex -> contrib -> boundary handoff via LDS ->
// barrier -> shift-by-1 (shfl + boundary) -> window mask -> renorm -> store.
// Log2 domain; store converts back to nats off the chain.
__global__ __launch_bounds__(512) void k_scan(const float* __restrict__ denom,
                                              const float* __restrict__ energy,
                                              float* __restrict__ prob) {
    int b = blockIdx.x;
    int j = threadIdx.x;            // 0..511
    int lane = j & 63, wv = j >> 6;
    __shared__ float wtm[8], wts[8], bqm[8], bqs[8];
    const float* dbase = denom + b * NI * NJ;
    const float* ebase = energy + b * NI * NJ;
    float* prow = prob + b * NI * NJ;

    prow[j] = (j == 0) ? 0.0f : NEG9;          // row 0
    Pair prev = (j == 0) ? Pair{0.0f, 1.0f} : Pair{NEG9, 1.0f};
    float cdn = dbase[j] * INVLN2;              // row 0 dn/en (log2)
    float cen = ebase[j] * INVLN2;

    for (int i = 1; i < NI; ++i) {
        float ndn = dbase[i * NJ + j];          // prefetch row i (raw)
        float nen = ebase[i * NJ + j];
        Pair q{prev.m - cdn, prev.s};
        Pair linc = wave_pair_scan(q);          // inclusive within wave
        if (lane == 63) { wtm[wv] = linc.m; wts[wv] = linc.s; }
        Pair wsh = shflup1(linc);               // within-wave exclusive
        if (lane == 0) wsh = {IDENT, 0.0f};
        __syncthreads();
        Pair w0{wtm[0], wts[0]}, w1{wtm[1], wts[1]}, w2{wtm[2], wts[2]}, w3{wtm[3], wts[3]};
        Pair w4{wtm[4], wts[4]}, w5{wtm[5], wts[5]}, w6{wtm[6], wts[6]}, w7{wtm[7], wts[7]};
        Pair t01 = pcomb(w0, w1), t23 = pcomb(w2, w3);
        Pair t45 = pcomb(w4, w5), t67 = pcomb(w6, w7);
        Pair t0123 = pcomb(t01, t23);
        Pair total = pcomb(t0123, pcomb(t45, t67));
        Pair wex;
        switch (wv) {                           // exclusive-by-wave offset (uniform)
            case 0: wex = {IDENT, 0.0f}; break;
            case 1: wex = w0; break;
            case 2: wex = t01; break;
            case 3: wex = pcomb(t01, w2); break;
            case 4: wex = t0123; break;
            case 5: wex = pcomb(t0123, w4); break;
            case 6: wex = pcomb(t0123, t45); break;
            default: wex = pcomb(pcomb(t0123, t45), w6); break;
        }
        Pair Pex = pcomb(wex, wsh);
        Pair sfx{total.m + LOGEPS2, total.s};
        Pair contrib = pcomb(Pair{cen + Pex.m, Pex.s}, sfx);
        if (lane == 63) { bqm[wv] = contrib.m; bqs[wv] = contrib.s; }
        __syncthreads();
        Pair csh = shflup1(contrib);            // shift by one: row[j] = contrib[j-1]
        if (lane == 0) csh = (wv > 0) ? Pair{bqm[wv - 1], bqs[wv - 1]} : Pair{NEG9, 1.0f};
        bool ok = (j >= i) && (j < i + 450);    // window, Jm=448
        Pair np = ok ? csh : Pair{NEG9, 1.0f};
        prow[i * NJ + j] = (np.m + log2f(np.s)) * LN2F;   // off-chain finalize (nats)
        // exact power-of-2 renorm: s in [0.5,1), m += k (log2 domain)
        int bits = __float_as_int(np.s);        // s in [0.5, ~1024] -> normal
        int k = (bits >> 23) - 126;
        prev.s = __int_as_float(bits - (k << 23));
        prev.m = np.m + (float)k;
        cdn = ndn * INVLN2; cen = nen * INVLN2;
    }
}

// ---------------- K5: soft + exp(soft); 1 wave per (b,i) row (R4-verified) ----------------
__global__ __launch_bounds__(64) void k_soft(const float* __restrict__ prob,
                                             const float* __restrict__ denom,
                                             const float* __restrict__ T,
                                             float* __restrict__ soft_out,
                                             float* __restrict__ w) {
    int bi = blockIdx.x;
    int lane = threadIdx.x;
    const float4* pr = (const float4*)(prob + bi * NJ);
    const float4* dr = (const float4*)(denom + bi * NJ);
    const float4* Tr = (const float4*)(T + bi * NJ);
    float4 p0 = pr[lane * 2], p1 = pr[lane * 2 + 1];
    float4 d0 = dr[lane * 2], d1 = dr[lane * 2 + 1];
    float4 t0 = Tr[lane * 2], t1 = Tr[lane * 2 + 1];
    float p[8] = {p0.x, p0.y, p0.z, p0.w, p1.x, p1.y, p1.z, p1.w};
    float dn[8] = {d0.x, d0.y, d0.z, d0.w, d1.x, d1.y, d1.z, d1.w};
    float Tl[8] = {t0.x, t0.y, t0.z, t0.w, t1.x, t1.y, t1.z, t1.w};
    float r[8], ls[8];
    #pragma unroll
    for (int t = 0; t < 8; ++t) r[t] = p[t] - dn[t];
    sklansky8(r, ls);
    float lin = wave_lse_scan(ls[7]);
    float offF = __shfl_up(lin, 1, 64);
    if (lane == 0) offF = IDENT;
    // total of p (suffix term == total, same fp32-exactness argument)
    float pA = lse2(lse2(lse2(p[0], p[1]), lse2(p[2], p[3])),
                    lse2(lse2(p[4], p[5]), lse2(p[6], p[7])));
    float ptot = bcast63(wave_lse_scan(pA));
    float sfx = ptot + LOGEPS;
    #pragma unroll
    for (int t = 0; t < 8; ++t) {
        float Pex = (t == 0) ? offF : lse2(offF, ls[t - 1]);
        float s = lse2(Tl[t] + Pex, sfx);
        int jj = lane * 8 + t;
        soft_out[bi * NJ + jj] = s;
        w[bi * NJ + jj] = __expf(s);
    }
}

// ---------------- K6: expanded[b,j,:] = sum_i w[b,i,j] * text[b,i,:] ----------------
__global__ __launch_bounds__(512) void k_expand(const float* __restrict__ w,
                                                const float* __restrict__ text,
                                                float* __restrict__ out2) {
    int bj = blockIdx.x; // b*NJ + j
    int d = threadIdx.x; // 512
    int b = bj >> 9, j = bj & (NJ - 1);
    float acc = 0.0f;
    #pragma unroll 4
    for (int i = 0; i < NI; ++i)
        acc = fmaf(w[(b * NI + i) * NJ + j], text[(b * NI + i) * NDT + d], acc);
    out2[bj * NDT + d] = acc;
}

extern "C" void kernel_launch(void* const* d_in, const int* in_sizes, int n_in,
                              void* d_out, int out_size, void* d_ws, size_t ws_size,
                              hipStream_t stream) {
    const float* text   = (const float*)d_in[0];
    const float* mel    = (const float*)d_in[1];
    const float* noise  = (const float*)d_in[2];
    const float* mel_w  = (const float*)d_in[5];
    const float* mel_b  = (const float*)d_in[6];
    const float* text_w = (const float*)d_in[7];
    const float* v_w    = (const float*)d_in[8];
    const float* v_b    = (const float*)d_in[9];

    float* ws = (float*)d_ws;
    float* pmT    = ws;                       // 2*128*512
    float* pt     = pmT + NB * NA * NJ;       // 2*64*128
    float* energy = pt + NB * NI * NA;        // 2*64*512
    float* T      = energy + NB * NI * NJ;    // 2*64*512
    float* denom  = T + NB * NI * NJ;         // 2*64*512
    float* prob   = denom + NB * NI * NJ;     // 2*64*512
    float* w      = prob + NB * NI * NJ;      // 2*64*512

    float* soft_out = (float*)d_out;              // 2*64*512
    float* out2     = soft_out + NB * NI * NJ;    // 2*512*512

    hipLaunchKernelGGL(k_proj,   dim3(NB * NJ + NB * NI), dim3(128), 0, stream,
                       text, mel, mel_w, mel_b, text_w, pmT, pt);
    hipLaunchKernelGGL(k_energy, dim3(NB * NI), dim3(512), 0, stream,
                       pmT, pt, v_w, v_b, noise, energy);
    hipLaunchKernelGGL(k_suffix, dim3(NB * NI), dim3(64), 0, stream,
                       energy, T, denom);
    hipLaunchKernelGGL(k_scan,   dim3(NB), dim3(512), 0, stream,
                       denom, energy, prob);
    hipLaunchKernelGGL(k_soft,   dim3(NB * NI), dim3(64), 0, stream,
                       prob, denom, T, soft_out, w);
    hipLaunchKernelGGL(k_expand, dim3(NB * NJ), dim3(512), 0, stream,
                       w, text, out2);
}

// Round 10
// 201.821 us; speedup vs baseline: 1.0685x; 1.0685x over previous
//
#include <hip/hip_runtime.h>
#include <math.h>

#define NB 2
#define NI 64
#define NJ 512
#define NDT 512
#define NDM 80
#define NA 128

#define NEG9    (-1000000000.0f)
#define LOGEPS  (-1000.0f)
#define IDENT   (-1.0e30f)
#define LN512   (6.2383246250f)
#define LN2F    (0.69314718056f)
#define INVLN2  (1.44269504089f)
#define LOGEPS2 (-1442.6950409f)   // -1000/ln2

__device__ __forceinline__ float lse2(float a, float b) {
    float m = fmaxf(a, b);
    float d = fabsf(a - b);
    return m + __logf(1.0f + __expf(-d));
}

// ---- (m,s) pair log-sum in LOG2 domain: value = m + log2(s) ---------------
// Single-exp select form: one exp2 per combine (halves transcendental issue
// vs the R8/R9 two-exp form; same dependent latency). Identity {IDENT, 0}
// combines exactly: exp2(-1e30)=0, fmaf(0,0,s)=s.
struct Pair { float m, s; };

__device__ __forceinline__ Pair pcomb(Pair a, Pair b) {
    float mm = fmaxf(a.m, b.m);
    float e  = exp2f(-fabsf(a.m - b.m));
    bool agt = a.m >= b.m;
    float hi = agt ? a.s : b.s;
    float lo = agt ? b.s : a.s;
    return {mm, fmaf(lo, e, hi)};
}

// DPP-based combines (row_shr/row_bcast ctrls HW-verified R4/R8/R9).
template<int CTRL, int RM>
__device__ __forceinline__ float dpp_lse(float s) {
    int v = __builtin_amdgcn_update_dpp(__float_as_int(IDENT), __float_as_int(s),
                                        CTRL, RM, 0xf, false);
    return lse2(s, __int_as_float(v));
}
template<int CTRL, int RM>
__device__ __forceinline__ Pair dpp_pcomb(Pair x) {
    int bm = __builtin_amdgcn_update_dpp(__float_as_int(IDENT), __float_as_int(x.m),
                                         CTRL, RM, 0xf, false);
    int bs = __builtin_amdgcn_update_dpp(0, __float_as_int(x.s),
                                         CTRL, RM, 0xf, false);
    Pair b{__int_as_float(bm), __int_as_float(bs)};
    return pcomb(x, b);
}

// Inclusive 64-lane scans (canonical gfx9 row_shr + row_bcast sequence).
__device__ __forceinline__ float wave_lse_scan(float x) {
    x = dpp_lse<0x111, 0xf>(x);
    x = dpp_lse<0x112, 0xf>(x);
    x = dpp_lse<0x114, 0xf>(x);
    x = dpp_lse<0x118, 0xf>(x);
    x = dpp_lse<0x142, 0xa>(x);
    x = dpp_lse<0x143, 0xc>(x);
    return x;
}
__device__ __forceinline__ Pair wave_pair_scan(Pair x) {
    x = dpp_pcomb<0x111, 0xf>(x);
    x = dpp_pcomb<0x112, 0xf>(x);
    x = dpp_pcomb<0x114, 0xf>(x);
    x = dpp_pcomb<0x118, 0xf>(x);
    x = dpp_pcomb<0x142, 0xa>(x);
    x = dpp_pcomb<0x143, 0xc>(x);
    return x;
}

__device__ __forceinline__ float bcast63(float x) {
    return __int_as_float(__builtin_amdgcn_readlane(__float_as_int(x), 63));
}
__device__ __forceinline__ Pair readp63(Pair x) {
    return { __int_as_float(__builtin_amdgcn_readlane(__float_as_int(x.m), 63)),
             __int_as_float(__builtin_amdgcn_readlane(__float_as_int(x.s), 63)) };
}
__device__ __forceinline__ Pair shflup1(Pair x) {
    return { __shfl_up(x.m, 1, 64), __shfl_up(x.s, 1, 64) };
}

// Inclusive 8-element Sklansky scans, depth 3.
__device__ __forceinline__ void sklansky8(const float* q, float* ls) {
    ls[0]=q[0]; ls[2]=q[2]; ls[4]=q[4]; ls[6]=q[6];
    ls[1]=lse2(q[0],q[1]); ls[3]=lse2(q[2],q[3]);
    ls[5]=lse2(q[4],q[5]); ls[7]=lse2(q[6],q[7]);
    ls[2]=lse2(ls[1],ls[2]); ls[3]=lse2(ls[1],ls[3]);
    ls[6]=lse2(ls[5],ls[6]); ls[7]=lse2(ls[5],ls[7]);
    ls[4]=lse2(ls[3],ls[4]); ls[5]=lse2(ls[3],ls[5]);
    ls[6]=lse2(ls[3],ls[6]); ls[7]=lse2(ls[3],ls[7]);
}
__device__ __forceinline__ void sklansky8p(const Pair* q, Pair* ls) {
    ls[0]=q[0]; ls[2]=q[2]; ls[4]=q[4]; ls[6]=q[6];
    ls[1]=pcomb(q[0],q[1]); ls[3]=pcomb(q[2],q[3]);
    ls[5]=pcomb(q[4],q[5]); ls[7]=pcomb(q[6],q[7]);
    ls[2]=pcomb(ls[1],ls[2]); ls[3]=pcomb(ls[1],ls[3]);
    ls[6]=pcomb(ls[5],ls[6]); ls[7]=pcomb(ls[5],ls[7]);
    ls[4]=pcomb(ls[3],ls[4]); ls[5]=pcomb(ls[3],ls[5]);
    ls[6]=pcomb(ls[3],ls[6]); ls[7]=pcomb(ls[3],ls[7]);
}

// ---------------- K1: projections pm (transposed) and pt ----------------
__global__ __launch_bounds__(128) void k_proj(const float* __restrict__ text,
                                              const float* __restrict__ mel,
                                              const float* __restrict__ mel_w,
                                              const float* __restrict__ mel_b,
                                              const float* __restrict__ text_w,
                                              float* __restrict__ pmT,
                                              float* __restrict__ pt) {
    __shared__ float row[NDT];
    int blk = blockIdx.x;
    int tid = threadIdx.x; // 128
    if (blk < NB * NJ) {
        int b = blk >> 9, j = blk & (NJ - 1);
        if (tid < NDM) row[tid] = mel[(b * NJ + j) * NDM + tid];
        __syncthreads();
        float acc = mel_b[tid];
        #pragma unroll 8
        for (int k = 0; k < NDM; ++k) acc = fmaf(row[k], mel_w[tid * NDM + k], acc);
        pmT[(b * NA + tid) * NJ + j] = acc;
    } else {
        int blk2 = blk - NB * NJ;
        int b = blk2 >> 6, i = blk2 & (NI - 1);
        for (int k = tid; k < NDT; k += 128) row[k] = text[(b * NI + i) * NDT + k];
        __syncthreads();
        float acc = 0.0f;
        #pragma unroll 8
        for (int k = 0; k < NDT; ++k) acc = fmaf(row[k], text_w[tid * NDT + k], acc);
        pt[(b * NI + i) * NA + tid] = acc;
    }
}

// ---------------- K2: energy = sigmoid(tanh(pm+pt)·v_w + v_b + 2*noise) ----------------
__global__ __launch_bounds__(512) void k_energy(const float* __restrict__ pmT,
                                                const float* __restrict__ pt,
                                                const float* __restrict__ v_w,
                                                const float* __restrict__ v_b,
                                                const float* __restrict__ noise,
                                                float* __restrict__ energy) {
    int bi = blockIdx.x;     // b*NI + i
    int j = threadIdx.x;     // 512
    int b = bi >> 6;
    __shared__ float pts[NA];
    __shared__ float vws[NA];
    if (j < NA) { pts[j] = pt[bi * NA + j]; vws[j] = v_w[j]; }
    __syncthreads();
    float acc = 0.0f;
    const float* pmb = pmT + b * NA * NJ + j;
    #pragma unroll 4
    for (int a = 0; a < NA; ++a) {
        float x = pmb[a * NJ] + pts[a];
        float t = __expf(2.0f * x);
        float th = 1.0f - 2.0f / (t + 1.0f);
        acc = fmaf(th, vws[a], acc);
    }
    float x = acc + v_b[0] + 2.0f * noise[bi * NJ + j];
    energy[bi * NJ + j] = 1.0f / (1.0f + __expf(-x));
}

// ---------------- K3: suffix-lse T and denom per (b,i) row (R4-verified) ----------------
__global__ __launch_bounds__(64) void k_suffix(const float* __restrict__ energy,
                                               float* __restrict__ T,
                                               float* __restrict__ denom) {
    int bi = blockIdx.x;
    int lane = threadIdx.x; // 64
    const float4* er = (const float4*)(energy + bi * NJ);
    float4 v0 = er[lane * 2], v1 = er[lane * 2 + 1];
    float q[8] = {v0.x, v0.y, v0.z, v0.w, v1.x, v1.y, v1.z, v1.w};
    float ss[8];
    ss[7] = q[7];
    #pragma unroll
    for (int t = 6; t >= 0; --t) ss[t] = lse2(q[t], ss[t + 1]);
    float tot = ss[0];
    #pragma unroll
    for (int off = 1; off < 64; off <<= 1) {
        float o = __shfl_down(tot, off, 64);
        if (lane + off < 64) tot = lse2(tot, o);
    }
    float offS = __shfl_down(tot, 1, 64);
    if (lane == 63) offS = IDENT;
    float Tl[8];
    #pragma unroll
    for (int t = 0; t < 8; ++t) Tl[t] = lse2(ss[t], offS);
    float4* Tr = (float4*)(T + bi * NJ);
    Tr[lane * 2]     = make_float4(Tl[0], Tl[1], Tl[2], Tl[3]);
    Tr[lane * 2 + 1] = make_float4(Tl[4], Tl[5], Tl[6], Tl[7]);
    // denom[k] = T[k+1]; denom[511] = -1000 + ln(512)
    float nextT0 = __shfl_down(Tl[0], 1, 64);
    float dn[8];
    #pragma unroll
    for (int t = 0; t < 7; ++t) dn[t] = Tl[t + 1];
    dn[7] = (lane == 63) ? (LOGEPS + LN512) : nextT0;
    float4* dr = (float4*)(denom + bi * NJ);
    dr[lane * 2]     = make_float4(dn[0], dn[1], dn[2], dn[3]);
    dr[lane * 2 + 1] = make_float4(dn[4], dn[5], dn[6], dn[7]);
}

// ---------------- K4: sequential forward scan; 1 wave/batch, SHIFTED FRAME ---
// Frame coordinate l = j - i (window-relative). prev_{i+1}[j] = contrib_i[j-1]
// lands at the SAME frame position (no shift on the chain); mask is the fixed
// l < 450 (plus l+i < 512, binding only at i=63); out-of-window columns carry
// exactly zero mass so the in-frame prefix equals the global prefix.
// Loads: element (i-1)*513 + l (linear, in-bounds; garbage only reaches
// masked lanes). Stores: j = (l+i) & 511 (bijective over the row).
__global__ __launch_bounds__(64) void k_scan(const float* __restrict__ denom,
                                             const float* __restrict__ energy,
                                             float* __restrict__ prob) {
    int b = blockIdx.x;
    int lane = threadIdx.x;
    int f = lane * 8;                    // frame base for this lane
    Pair prev[8];
    #pragma unroll
    for (int t = 0; t < 8; ++t) prev[t] = {NEG9, 1.0f};
    if (lane == 0) prev[0] = {0.0f, 1.0f};
    float* prow = prob + b * NI * NJ;
    {   // row 0 (frame == global at i=0)
        float4* pr = (float4*)prow;
        pr[lane * 2]     = make_float4(prev[0].m, prev[1].m, prev[2].m, prev[3].m);
        pr[lane * 2 + 1] = make_float4(prev[4].m, prev[5].m, prev[6].m, prev[7].m);
    }
    const float* dbase = denom + b * NI * NJ;
    const float* ebase = energy + b * NI * NJ;
    // cdn/cen: row consumed THIS iteration (log2 domain); ndn/nen: next (raw)
    float cdn[8], cen[8], ndn[8], nen[8];
    #pragma unroll
    for (int t = 0; t < 8; ++t) {
        cdn[t] = dbase[f + t] * INVLN2;          // iter 1: (1-1)*513 + l
        cen[t] = ebase[f + t] * INVLN2;
        ndn[t] = dbase[513 + f + t];             // iter 2: (2-1)*513 + l
        nen[t] = ebase[513 + f + t];
    }
    for (int i = 1; i < NI; ++i) {
        // issue loads for iteration i+2 (consumed two iterations ahead)
        float fd[8], fe[8];
        #pragma unroll
        for (int t = 0; t < 8; ++t) { fd[t] = ndn[t]; fe[t] = nen[t]; }
        if (i <= NI - 3) {
            int base = (i + 1) * (NJ + 1) + f;   // max 62*513+511 = 32317 < 32768
            #pragma unroll
            for (int t = 0; t < 8; ++t) { fd[t] = dbase[base + t]; fe[t] = ebase[base + t]; }
        }
        Pair q[8], ls[8];
        #pragma unroll
        for (int t = 0; t < 8; ++t) q[t] = {prev[t].m - cdn[t], prev[t].s};
        sklansky8p(q, ls);
        Pair lin = wave_pair_scan(ls[7]);        // lane-inclusive
        Pair total = readp63(lin);
        Pair offF = shflup1(lin);                // lane-exclusive offset
        if (lane == 0) offF = {IDENT, 0.0f};
        Pair sfx = {total.m + LOGEPS2, total.s};
        Pair np[8];
        #pragma unroll
        for (int t = 0; t < 8; ++t) {
            Pair Pex = (t == 0) ? offF : pcomb(offF, ls[t - 1]);
            np[t] = pcomb(Pair{cen[t] + Pex.m, Pex.s}, sfx);
        }
        // fixed frame mask: l < 450 (window), l + i < 512 (row end, i=63 only)
        #pragma unroll
        for (int t = 0; t < 8; ++t) {
            int l = f + t;
            bool ok = (l < 450) && (l + i < 512);
            np[t] = ok ? np[t] : Pair{NEG9, 1.0f};
        }
        // store row i at wrapped global column; finalize off-chain (nats)
        #pragma unroll
        for (int t = 0; t < 8; ++t) {
            int j = (f + t + i) & (NJ - 1);
            prow[i * NJ + j] = (np[t].m + log2f(np[t].s)) * LN2F;
        }
        // exact power-of-2 renorm of the carry (log2 domain): s in [0.5,1)
        #pragma unroll
        for (int t = 0; t < 8; ++t) {
            int bits = __float_as_int(np[t].s);
            int k = (bits >> 23) - 126;
            prev[t].s = __int_as_float(bits - (k << 23));
            prev[t].m = np[t].m + (float)k;
        }
        // rotate rows (apply log2 scale off-chain)
        #pragma unroll
        for (int t = 0; t < 8; ++t) {
            cdn[t] = ndn[t] * INVLN2; cen[t] = nen[t] * INVLN2;
            ndn[t] = fd[t];           nen[t] = fe[t];
        }
    }
}

// ---------------- K5: soft + exp(soft); 1 wave per (b,i) row (R4-verified) ----------------
__global__ __launch_bounds__(64) void k_soft(const float* __restrict__ prob,
                                             const float* __restrict__ denom,
                                             const float* __restrict__ T,
                                             float* __restrict__ soft_out,
                                             float* __restrict__ w) {
    int bi = blockIdx.x;
    int lane = threadIdx.x;
    const float4* pr = (const float4*)(prob + bi * NJ);
    const float4* dr = (const float4*)(denom + bi * NJ);
    const float4* Tr = (const float4*)(T + bi * NJ);
    float4 p0 = pr[lane * 2], p1 = pr[lane * 2 + 1];
    float4 d0 = dr[lane * 2], d1 = dr[lane * 2 + 1];
    float4 t0 = Tr[lane * 2], t1 = Tr[lane * 2 + 1];
    float p[8] = {p0.x, p0.y, p0.z, p0.w, p1.x, p1.y, p1.z, p1.w};
    float dn[8] = {d0.x, d0.y, d0.z, d0.w, d1.x, d1.y, d1.z, d1.w};
    float Tl[8] = {t0.x, t0.y, t0.z, t0.w, t1.x, t1.y, t1.z, t1.w};
    float r[8], ls[8];
    #pragma unroll
    for (int t = 0; t < 8; ++t) r[t] = p[t] - dn[t];
    sklansky8(r, ls);
    float lin = wave_lse_scan(ls[7]);
    float offF = __shfl_up(lin, 1, 64);
    if (lane == 0) offF = IDENT;
    // total of p (suffix term == total, same fp32-exactness argument)
    float pA = lse2(lse2(lse2(p[0], p[1]), lse2(p[2], p[3])),
                    lse2(lse2(p[4], p[5]), lse2(p[6], p[7])));
    float ptot = bcast63(wave_lse_scan(pA));
    float sfx = ptot + LOGEPS;
    #pragma unroll
    for (int t = 0; t < 8; ++t) {
        float Pex = (t == 0) ? offF : lse2(offF, ls[t - 1]);
        float s = lse2(Tl[t] + Pex, sfx);
        int jj = lane * 8 + t;
        soft_out[bi * NJ + jj] = s;
        w[bi * NJ + jj] = __expf(s);
    }
}

// ---------------- K6: expanded[b,j,:] = sum_i w[b,i,j] * text[b,i,:] ----------------
__global__ __launch_bounds__(512) void k_expand(const float* __restrict__ w,
                                                const float* __restrict__ text,
                                                float* __restrict__ out2) {
    int bj = blockIdx.x; // b*NJ + j
    int d = threadIdx.x; // 512
    int b = bj >> 9, j = bj & (NJ - 1);
    float acc = 0.0f;
    #pragma unroll 4
    for (int i = 0; i < NI; ++i)
        acc = fmaf(w[(b * NI + i) * NJ + j], text[(b * NI + i) * NDT + d], acc);
    out2[bj * NDT + d] = acc;
}

extern "C" void kernel_launch(void* const* d_in, const int* in_sizes, int n_in,
                              void* d_out, int out_size, void* d_ws, size_t ws_size,
                              hipStream_t stream) {
    const float* text   = (const float*)d_in[0];
    const float* mel    = (const float*)d_in[1];
    const float* noise  = (const float*)d_in[2];
    const float* mel_w  = (const float*)d_in[5];
    const float* mel_b  = (const float*)d_in[6];
    const float* text_w = (const float*)d_in[7];
    const float* v_w    = (const float*)d_in[8];
    const float* v_b    = (const float*)d_in[9];

    float* ws = (float*)d_ws;
    float* pmT    = ws;                       // 2*128*512
    float* pt     = pmT + NB * NA * NJ;       // 2*64*128
    float* energy = pt + NB * NI * NA;        // 2*64*512
    float* T      = energy + NB * NI * NJ;    // 2*64*512
    float* denom  = T + NB * NI * NJ;         // 2*64*512
    float* prob   = denom + NB * NI * NJ;     // 2*64*512
    float* w      = prob + NB * NI * NJ;      // 2*64*512

    float* soft_out = (float*)d_out;              // 2*64*512
    float* out2     = soft_out + NB * NI * NJ;    // 2*512*512

    hipLaunchKernelGGL(k_proj,   dim3(NB * NJ + NB * NI), dim3(128), 0, stream,
                       text, mel, mel_w, mel_b, text_w, pmT, pt);
    hipLaunchKernelGGL(k_energy, dim3(NB * NI), dim3(512), 0, stream,
                       pmT, pt, v_w, v_b, noise, energy);
    hipLaunchKernelGGL(k_suffix, dim3(NB * NI), dim3(64), 0, stream,
                       energy, T, denom);
    hipLaunchKernelGGL(k_scan,   dim3(NB), dim3(64), 0, stream,
                       denom, energy, prob);
    hipLaunchKernelGGL(k_soft,   dim3(NB * NI), dim3(64), 0, stream,
                       prob, denom, T, soft_out, w);
    hipLaunchKernelGGL(k_expand, dim3(NB * NJ), dim3(512), 0, stream,
                       w, text, out2);
}

// Round 11
// 189.560 us; speedup vs baseline: 1.1376x; 1.0647x over previous
//
#include <hip/hip_runtime.h>
#include <math.h>

#define NB 2
#define NI 64
#define NJ 512
#define NDT 512
#define NDM 80
#define NA 128

#define NEG9    (-1000000000.0f)
#define LOGEPS  (-1000.0f)
#define IDENT   (-1.0e30f)
#define LN512   (6.2383246250f)
#define LN2F    (0.69314718056f)
#define INVLN2  (1.44269504089f)
#define LOGEPS2 (-1442.6950409f)   // -1000/ln2

__device__ __forceinline__ float lse2(float a, float b) {
    float m = fmaxf(a, b);
    float d = fabsf(a - b);
    return m + __logf(1.0f + __expf(-d));
}

// ---- (m,s) pair log-sum in LOG2 domain: value = m + log2(s) ---------------
// Single-exp select form (R10-verified numerics). Identity {IDENT,0} combines
// exactly. Carries across >O(1000) combines need the power-of-2 renorm
// (R5/R6 NaN root cause); intra-row scans (<=512 terms) need none.
struct Pair { float m, s; };

__device__ __forceinline__ Pair pcomb(Pair a, Pair b) {
    float mm = fmaxf(a.m, b.m);
    float e  = exp2f(-fabsf(a.m - b.m));
    bool agt = a.m >= b.m;
    float hi = agt ? a.s : b.s;
    float lo = agt ? b.s : a.s;
    return {mm, fmaf(lo, e, hi)};
}

// DPP-based combines (row_shr/row_bcast ctrls HW-verified R4/R8/R9/R10).
template<int CTRL, int RM>
__device__ __forceinline__ float dpp_lse(float s) {
    int v = __builtin_amdgcn_update_dpp(__float_as_int(IDENT), __float_as_int(s),
                                        CTRL, RM, 0xf, false);
    return lse2(s, __int_as_float(v));
}
template<int CTRL, int RM>
__device__ __forceinline__ Pair dpp_pcomb(Pair x) {
    int bm = __builtin_amdgcn_update_dpp(__float_as_int(IDENT), __float_as_int(x.m),
                                         CTRL, RM, 0xf, false);
    int bs = __builtin_amdgcn_update_dpp(0, __float_as_int(x.s),
                                         CTRL, RM, 0xf, false);
    Pair b{__int_as_float(bm), __int_as_float(bs)};
    return pcomb(x, b);
}

// Inclusive 64-lane scans (canonical gfx9 row_shr + row_bcast sequence).
__device__ __forceinline__ float wave_lse_scan(float x) {
    x = dpp_lse<0x111, 0xf>(x);
    x = dpp_lse<0x112, 0xf>(x);
    x = dpp_lse<0x114, 0xf>(x);
    x = dpp_lse<0x118, 0xf>(x);
    x = dpp_lse<0x142, 0xa>(x);
    x = dpp_lse<0x143, 0xc>(x);
    return x;
}
__device__ __forceinline__ Pair wave_pair_scan(Pair x) {
    x = dpp_pcomb<0x111, 0xf>(x);
    x = dpp_pcomb<0x112, 0xf>(x);
    x = dpp_pcomb<0x114, 0xf>(x);
    x = dpp_pcomb<0x118, 0xf>(x);
    x = dpp_pcomb<0x142, 0xa>(x);
    x = dpp_pcomb<0x143, 0xc>(x);
    return x;
}

__device__ __forceinline__ float bcast63(float x) {
    return __int_as_float(__builtin_amdgcn_readlane(__float_as_int(x), 63));
}
__device__ __forceinline__ Pair readp63(Pair x) {
    return { __int_as_float(__builtin_amdgcn_readlane(__float_as_int(x.m), 63)),
             __int_as_float(__builtin_amdgcn_readlane(__float_as_int(x.s), 63)) };
}
__device__ __forceinline__ Pair shflup1(Pair x) {
    return { __shfl_up(x.m, 1, 64), __shfl_up(x.s, 1, 64) };
}

// Inclusive 8-element Sklansky scans, depth 3.
__device__ __forceinline__ void sklansky8(const float* q, float* ls) {
    ls[0]=q[0]; ls[2]=q[2]; ls[4]=q[4]; ls[6]=q[6];
    ls[1]=lse2(q[0],q[1]); ls[3]=lse2(q[2],q[3]);
    ls[5]=lse2(q[4],q[5]); ls[7]=lse2(q[6],q[7]);
    ls[2]=lse2(ls[1],ls[2]); ls[3]=lse2(ls[1],ls[3]);
    ls[6]=lse2(ls[5],ls[6]); ls[7]=lse2(ls[5],ls[7]);
    ls[4]=lse2(ls[3],ls[4]); ls[5]=lse2(ls[3],ls[5]);
    ls[6]=lse2(ls[3],ls[6]); ls[7]=lse2(ls[3],ls[7]);
}
__device__ __forceinline__ void sklansky8p(const Pair* q, Pair* ls) {
    ls[0]=q[0]; ls[2]=q[2]; ls[4]=q[4]; ls[6]=q[6];
    ls[1]=pcomb(q[0],q[1]); ls[3]=pcomb(q[2],q[3]);
    ls[5]=pcomb(q[4],q[5]); ls[7]=pcomb(q[6],q[7]);
    ls[2]=pcomb(ls[1],ls[2]); ls[3]=pcomb(ls[1],ls[3]);
    ls[6]=pcomb(ls[5],ls[6]); ls[7]=pcomb(ls[5],ls[7]);
    ls[4]=pcomb(ls[3],ls[4]); ls[5]=pcomb(ls[3],ls[5]);
    ls[6]=pcomb(ls[3],ls[6]); ls[7]=pcomb(ls[3],ls[7]);
}

// ---------------- K1: projections pm (transposed) and pt ----------------
__global__ __launch_bounds__(128) void k_proj(const float* __restrict__ text,
                                              const float* __restrict__ mel,
                                              const float* __restrict__ mel_w,
                                              const float* __restrict__ mel_b,
                                              const float* __restrict__ text_w,
                                              float* __restrict__ pmT,
                                              float* __restrict__ pt) {
    __shared__ float row[NDT];
    int blk = blockIdx.x;
    int tid = threadIdx.x; // 128
    if (blk < NB * NJ) {
        int b = blk >> 9, j = blk & (NJ - 1);
        if (tid < NDM) row[tid] = mel[(b * NJ + j) * NDM + tid];
        __syncthreads();
        float acc = mel_b[tid];
        #pragma unroll 8
        for (int k = 0; k < NDM; ++k) acc = fmaf(row[k], mel_w[tid * NDM + k], acc);
        pmT[(b * NA + tid) * NJ + j] = acc;
    } else {
        int blk2 = blk - NB * NJ;
        int b = blk2 >> 6, i = blk2 & (NI - 1);
        for (int k = tid; k < NDT; k += 128) row[k] = text[(b * NI + i) * NDT + k];
        __syncthreads();
        float acc = 0.0f;
        #pragma unroll 8
        for (int k = 0; k < NDT; ++k) acc = fmaf(row[k], text_w[tid * NDT + k], acc);
        pt[(b * NI + i) * NA + tid] = acc;
    }
}

// ---------------- K2: energy + suffix-lse T + denom (fused; 6->5 kernels) --
// Safe now: intra-row pair scans span <=512 terms (s <= 512, no overflow);
// the R5-era NaN was the unrenormalized 63-iter carry in k_scan, not this.
__global__ __launch_bounds__(512) void k_energy(const float* __restrict__ pmT,
                                                const float* __restrict__ pt,
                                                const float* __restrict__ v_w,
                                                const float* __restrict__ v_b,
                                                const float* __restrict__ noise,
                                                float* __restrict__ energy,
                                                float* __restrict__ T,
                                                float* __restrict__ denom) {
    int bi = blockIdx.x;     // b*NI + i
    int j = threadIdx.x;     // 512
    int b = bi >> 6;
    int lane = j & 63, wv = j >> 6;
    __shared__ float pts[NA];
    __shared__ float vws[NA];
    __shared__ float wtm[8], wts[8];
    __shared__ float Ta[NJ];
    if (j < NA) { pts[j] = pt[bi * NA + j]; vws[j] = v_w[j]; }
    __syncthreads();
    float acc = 0.0f;
    const float* pmb = pmT + b * NA * NJ + j;
    #pragma unroll 4
    for (int a = 0; a < NA; ++a) {
        float x = pmb[a * NJ] + pts[a];
        float t = __expf(2.0f * x);
        float th = 1.0f - 2.0f / (t + 1.0f);
        acc = fmaf(th, vws[a], acc);
    }
    float x = acc + v_b[0] + 2.0f * noise[bi * NJ + j];
    float e = 1.0f / (1.0f + __expf(-x));
    energy[bi * NJ + j] = e;
    // --- suffix-lse via reversed pair prefix scan (log2 domain) ---
    float el2 = e * INVLN2;
    float er = __shfl(el2, 63 - lane, 64);            // reversed within wave
    Pair pr = wave_pair_scan({er, 1.0f});             // prefix of reversed
    if (lane == 63) { wtm[wv] = pr.m; wts[wv] = pr.s; }
    float sfm = __shfl(pr.m, 63 - lane, 64);          // reverse back
    float sfs = __shfl(pr.s, 63 - lane, 64);          //  -> within-wave suffix
    __syncthreads();
    Pair tail = {IDENT, 0.0f};
    for (int w2 = wv + 1; w2 < 8; ++w2) tail = pcomb(tail, {wtm[w2], wts[w2]});
    Pair Tp = pcomb({sfm, sfs}, tail);
    float Tlog = (Tp.m + log2f(Tp.s)) * LN2F;         // back to nats
    Ta[j] = Tlog;
    T[bi * NJ + j] = Tlog;
    __syncthreads();
    denom[bi * NJ + j] = (j < NJ - 1) ? Ta[j + 1] : (LOGEPS + LN512);
}

// ---------------- K3: sequential forward scan; 1 wave per batch ----------------
// R8-verified layout (float4 aligned loads/stores, global frame, shift via
// shfl_up) + single-exp log2 pcomb (R10-verified numerics) + pair output
// (finalization logs moved to k_soft).
__global__ __launch_bounds__(64) void k_scan(const float* __restrict__ denom,
                                             const float* __restrict__ energy,
                                             float* __restrict__ pmP,
                                             float* __restrict__ psP) {
    int b = blockIdx.x;
    int lane = threadIdx.x;
    Pair prev[8];
    #pragma unroll
    for (int t = 0; t < 8; ++t) prev[t] = {NEG9, 1.0f};
    if (lane == 0) prev[0] = {0.0f, 1.0f};
    float* pmrow = pmP + b * NI * NJ;
    float* psrow = psP + b * NI * NJ;
    {   // row 0
        float4* pm = (float4*)pmrow;
        float4* ps = (float4*)psrow;
        pm[lane * 2]     = make_float4(prev[0].m, prev[1].m, prev[2].m, prev[3].m);
        pm[lane * 2 + 1] = make_float4(prev[4].m, prev[5].m, prev[6].m, prev[7].m);
        ps[lane * 2]     = make_float4(1.0f, 1.0f, 1.0f, 1.0f);
        ps[lane * 2 + 1] = make_float4(1.0f, 1.0f, 1.0f, 1.0f);
    }
    const float4* dp = (const float4*)(denom + b * NI * NJ);
    const float4* ep = (const float4*)(energy + b * NI * NJ);
    float4 cd0 = dp[lane * 2], cd1 = dp[lane * 2 + 1];
    float4 ce0 = ep[lane * 2], ce1 = ep[lane * 2 + 1];
    float4 nd0 = dp[(NJ >> 2) + lane * 2], nd1 = dp[(NJ >> 2) + lane * 2 + 1];
    float4 ne0 = ep[(NJ >> 2) + lane * 2], ne1 = ep[(NJ >> 2) + lane * 2 + 1];
    for (int i = 1; i < NI; ++i) {
        // issue row i+1 (consumed at iter i+2)
        float4 fd0 = cd0, fd1 = cd1, fe0 = ce0, fe1 = ce1;
        if (i < NI - 2) {
            int base = (i + 1) * (NJ >> 2) + lane * 2;
            fd0 = dp[base]; fd1 = dp[base + 1];
            fe0 = ep[base]; fe1 = ep[base + 1];
        }
        float dn[8] = {cd0.x, cd0.y, cd0.z, cd0.w, cd1.x, cd1.y, cd1.z, cd1.w};
        float en[8] = {ce0.x, ce0.y, ce0.z, ce0.w, ce1.x, ce1.y, ce1.z, ce1.w};
        Pair q[8], ls[8];
        #pragma unroll
        for (int t = 0; t < 8; ++t) q[t] = {prev[t].m - dn[t] * INVLN2, prev[t].s};
        sklansky8p(q, ls);
        Pair lin = wave_pair_scan(ls[7]);      // lane-inclusive
        Pair total = readp63(lin);
        Pair offF = shflup1(lin);              // lane-exclusive offset
        if (lane == 0) offF = {IDENT, 0.0f};
        Pair sfx = {total.m + LOGEPS2, total.s};
        Pair contrib[8];
        #pragma unroll
        for (int t = 0; t < 8; ++t) {
            Pair Pex = (t == 0) ? offF : pcomb(offF, ls[t - 1]);
            contrib[t] = pcomb(Pair{en[t] * INVLN2 + Pex.m, Pex.s}, sfx);
        }
        // shift by one: row[j] = contrib[j-1]; then window mask
        Pair c7 = shflup1(contrib[7]);
        Pair np[8];
        np[0] = c7;
        #pragma unroll
        for (int t = 1; t < 8; ++t) np[t] = contrib[t - 1];
        #pragma unroll
        for (int t = 0; t < 8; ++t) {
            int j = lane * 8 + t;
            bool ok = (j >= i) && (j < i + 450);   // window, Jm=448
            prev[t] = ok ? np[t] : Pair{NEG9, 1.0f};
        }
        // store pairs (off the serial chain; finalize deferred to k_soft)
        float4* pm = (float4*)(pmrow + i * NJ);
        float4* ps = (float4*)(psrow + i * NJ);
        pm[lane * 2]     = make_float4(prev[0].m, prev[1].m, prev[2].m, prev[3].m);
        pm[lane * 2 + 1] = make_float4(prev[4].m, prev[5].m, prev[6].m, prev[7].m);
        ps[lane * 2]     = make_float4(prev[0].s, prev[1].s, prev[2].s, prev[3].s);
        ps[lane * 2 + 1] = make_float4(prev[4].s, prev[5].s, prev[6].s, prev[7].s);
        // exact power-of-2 renorm of the carry: s in [0.5,1), m += k (log2)
        #pragma unroll
        for (int t = 0; t < 8; ++t) {
            int bits = __float_as_int(prev[t].s);
            int k = (bits >> 23) - 126;
            prev[t].s = __int_as_float(bits - (k << 23));
            prev[t].m = prev[t].m + (float)k;
        }
        // rotate ring
        cd0 = nd0; cd1 = nd1; ce0 = ne0; ce1 = ne1;
        nd0 = fd0; nd1 = fd1; ne0 = fe0; ne1 = fe1;
    }
}

// ---------------- K4: soft + exp(soft); 1 wave per (b,i) row --------------
// Reads (m,s) pairs, finalizes p = (m + log2 s)*ln2 (parallel, off k_scan's
// critical path), then R4-verified lse2 structure.
__global__ __launch_bounds__(64) void k_soft(const float* __restrict__ pmP,
                                             const float* __restrict__ psP,
                                             const float* __restrict__ denom,
                                             const float* __restrict__ T,
                                             float* __restrict__ soft_out,
                                             float* __restrict__ w) {
    int bi = blockIdx.x;
    int lane = threadIdx.x;
    const float4* pmr = (const float4*)(pmP + bi * NJ);
    const float4* psr = (const float4*)(psP + bi * NJ);
    const float4* dr = (const float4*)(denom + bi * NJ);
    const float4* Tr = (const float4*)(T + bi * NJ);
    float4 m0 = pmr[lane * 2], m1 = pmr[lane * 2 + 1];
    float4 s0 = psr[lane * 2], s1 = psr[lane * 2 + 1];
    float4 d0 = dr[lane * 2], d1 = dr[lane * 2 + 1];
    float4 t0 = Tr[lane * 2], t1 = Tr[lane * 2 + 1];
    float pm[8] = {m0.x, m0.y, m0.z, m0.w, m1.x, m1.y, m1.z, m1.w};
    float psv[8] = {s0.x, s0.y, s0.z, s0.w, s1.x, s1.y, s1.z, s1.w};
    float dn[8] = {d0.x, d0.y, d0.z, d0.w, d1.x, d1.y, d1.z, d1.w};
    float Tl[8] = {t0.x, t0.y, t0.z, t0.w, t1.x, t1.y, t1.z, t1.w};
    float p[8];
    #pragma unroll
    for (int t = 0; t < 8; ++t) p[t] = (pm[t] + log2f(psv[t])) * LN2F;
    float r[8], ls[8];
    #pragma unroll
    for (int t = 0; t < 8; ++t) r[t] = p[t] - dn[t];
    sklansky8(r, ls);
    float lin = wave_lse_scan(ls[7]);
    float offF = __shfl_up(lin, 1, 64);
    if (lane == 0) offF = IDENT;
    // total of p (suffix term == total, same fp32-exactness argument)
    float pA = lse2(lse2(lse2(p[0], p[1]), lse2(p[2], p[3])),
                    lse2(lse2(p[4], p[5]), lse2(p[6], p[7])));
    float ptot = bcast63(wave_lse_scan(pA));
    float sfx = ptot + LOGEPS;
    #pragma unroll
    for (int t = 0; t < 8; ++t) {
        float Pex = (t == 0) ? offF : lse2(offF, ls[t - 1]);
        float s = lse2(Tl[t] + Pex, sfx);
        int jj = lane * 8 + t;
        soft_out[bi * NJ + jj] = s;
        w[bi * NJ + jj] = __expf(s);
    }
}

// ---------------- K5: expanded[b,j,:] = sum_i w[b,i,j] * text[b,i,:] -------
__global__ __launch_bounds__(512) void k_expand(const float* __restrict__ w,
                                                const float* __restrict__ text,
                                                float* __restrict__ out2) {
    int bj = blockIdx.x; // b*NJ + j
    int d = threadIdx.x; // 512
    int b = bj >> 9, j = bj & (NJ - 1);
    float acc = 0.0f;
    #pragma unroll 4
    for (int i = 0; i < NI; ++i)
        acc = fmaf(w[(b * NI + i) * NJ + j], text[(b * NI + i) * NDT + d], acc);
    out2[bj * NDT + d] = acc;
}

extern "C" void kernel_launch(void* const* d_in, const int* in_sizes, int n_in,
                              void* d_out, int out_size, void* d_ws, size_t ws_size,
                              hipStream_t stream) {
    const float* text   = (const float*)d_in[0];
    const float* mel    = (const float*)d_in[1];
    const float* noise  = (const float*)d_in[2];
    const float* mel_w  = (const float*)d_in[5];
    const float* mel_b  = (const float*)d_in[6];
    const float* text_w = (const float*)d_in[7];
    const float* v_w    = (const float*)d_in[8];
    const float* v_b    = (const float*)d_in[9];

    float* ws = (float*)d_ws;
    float* pmT    = ws;                       // 2*128*512
    float* pt     = pmT + NB * NA * NJ;       // 2*64*128
    float* energy = pt + NB * NI * NA;        // 2*64*512
    float* T      = energy + NB * NI * NJ;    // 2*64*512
    float* denom  = T + NB * NI * NJ;         // 2*64*512
    float* pmP    = denom + NB * NI * NJ;     // 2*64*512 (pair m)
    float* psP    = pmP + NB * NI * NJ;       // 2*64*512 (pair s)
    float* w      = psP + NB * NI * NJ;       // 2*64*512

    float* soft_out = (float*)d_out;              // 2*64*512
    float* out2     = soft_out + NB * NI * NJ;    // 2*512*512

    hipLaunchKernelGGL(k_proj,   dim3(NB * NJ + NB * NI), dim3(128), 0, stream,
                       text, mel, mel_w, mel_b, text_w, pmT, pt);
    hipLaunchKernelGGL(k_energy, dim3(NB * NI), dim3(512), 0, stream,
                       pmT, pt, v_w, v_b, noise, energy, T, denom);
    hipLaunchKernelGGL(k_scan,   dim3(NB), dim3(64), 0, stream,
                       denom, energy, pmP, psP);
    hipLaunchKernelGGL(k_soft,   dim3(NB * NI), dim3(64), 0, stream,
                       pmP, psP, denom, T, soft_out, w);
    hipLaunchKernelGGL(k_expand, dim3(NB * NJ), dim3(512), 0, stream,
                       w, text, out2);
}